// Round 3
// baseline (1226.064 us; speedup 1.0000x reference)
//
#include <hip/hip_runtime.h>
#include <hip/hip_fp16.h>

typedef _Float16 f16;
typedef _Float16 f16x2 __attribute__((ext_vector_type(2)));
typedef _Float16 f16x8 __attribute__((ext_vector_type(8)));
typedef float    f32x4 __attribute__((ext_vector_type(4)));

#define NB   8192
#define TOUT 10
#define LMAX 12
#define EMB  300

__device__ __forceinline__ float sigm_(float x) {
    return __builtin_amdgcn_rcpf(1.0f + __builtin_amdgcn_exp2f(x * -1.44269504f));
}
__device__ __forceinline__ float tanh_(float x) {
    return 1.0f - 2.0f * __builtin_amdgcn_rcpf(1.0f + __builtin_amdgcn_exp2f(x * 2.88539008f));
}

__device__ __forceinline__ f16x2 pk_f16(float a, float b) {
    return __builtin_bit_cast(f16x2, __builtin_amdgcn_cvt_pkrtz(a, b));
}

// ---------------------------------------------------------------------------
// K0a: pack LSTM weights into MFMA B-fragment tiles, f16, gate-permuted cols.
// Dest per dir: [kc 0..15][ntile 0..63][512 f16]; within tile element (k,n):
// offset = ((k%32)/8*16 + n%16)*8 + k%8 (lane l reads l*8..l*8+7).
// Column permutation: n -> w=n/128, rr=n%128, gate=rr>>5, us=(rr>>4)&1,
// l16=rr&15, unit u = w*32 + 2*l16 + us  (lane's us=0/1 values LDS-adjacent).
// ---------------------------------------------------------------------------
__global__ __launch_bounds__(256) void pack_w2(
    const float* __restrict__ wih_f, const float* __restrict__ whh_f,
    const float* __restrict__ wih_b, const float* __restrict__ whh_b,
    f16* __restrict__ Wp) {
    int idx = blockIdx.x * 256 + threadIdx.x;   // 0 .. 2*524288-1
    int d   = idx >> 19;
    int r   = idx & 524287;
    int tile = r >> 9;
    int e    = r & 511;
    int kc = tile >> 6, nt = tile & 63;
    int khi = e >> 7, rem = e & 127, nl = rem >> 3, klo = rem & 7;
    int n = nt * 16 + nl;
    int k = kc * 32 + khi * 8 + klo;
    int w = n >> 7, rr = n & 127, gate = rr >> 5;
    int u = w * 32 + 2 * (rr & 15) + ((rr >> 4) & 1);
    int srow = gate * 256 + u;
    const float* wih = d ? wih_b : wih_f;
    const float* whh = d ? whh_b : whh_f;
    float v = (k < 256) ? wih[srow * 256 + k] : whh[srow * 256 + (k - 256)];
    Wp[idx] = (f16)v;
}

__global__ __launch_bounds__(256) void pack_bias(
    const float* __restrict__ bih_f, const float* __restrict__ bhh_f,
    const float* __restrict__ bih_b, const float* __restrict__ bhh_b,
    float* __restrict__ bp) {
    int idx = blockIdx.x * 256 + threadIdx.x;   // 2048
    int d = idx >> 10, n = idx & 1023;
    int w = n >> 7, rr = n & 127, gate = rr >> 5;
    int u = w * 32 + 2 * (rr & 15) + ((rr >> 4) & 1);
    int srow = gate * 256 + u;
    bp[idx] = d ? (bih_b[srow] + bhh_b[srow]) : (bih_f[srow] + bhh_f[srow]);
}

// K0b: pack out_w (512x512) into B-fragment tiles: [kc 0..15][ntile 0..31][512]
__global__ __launch_bounds__(256) void pack_w3(
    const float* __restrict__ out_w, f16* __restrict__ W3p) {
    int idx = blockIdx.x * 256 + threadIdx.x;   // 262144
    int tile = idx >> 9, e = idx & 511;
    int kc = tile >> 5, nt = tile & 31;
    int khi = e >> 7, rem = e & 127, nl = rem >> 3, klo = rem & 7;
    int n = nt * 16 + nl, k = kc * 32 + khi * 8 + klo;
    W3p[idx] = (f16)out_w[n * 512 + k];
}

// K0c: P[36][256] = emb_table @ enc_w^T + enc_b (fp32)
__global__ __launch_bounds__(256) void enc_proj(
    const float* __restrict__ tab, const float* __restrict__ ew,
    const float* __restrict__ eb, float* __restrict__ P) {
    int v = blockIdx.x, j = threadIdx.x;
    const float* a = tab + v * EMB;
    const float* w = ew + j * EMB;
    float s = 0.0f;
    for (int k = 0; k < EMB; ++k) s += a[k] * w[k];
    P[v * 256 + j] = s + eb[j];
}

// ---------------------------------------------------------------------------
// K1: build seq in MFMA A-fragment tile layout, f16.
// seqp: [t 0..9][mtile 0..511][kc 0..7][512 f16]; element (row,k):
// offset = ((k%32)/8*16 + row%16)*8 + k%8
// ---------------------------------------------------------------------------
__global__ __launch_bounds__(256) void build_seq(
    const int* __restrict__ words, const int* __restrict__ lengths,
    const float* __restrict__ P, f16* __restrict__ seqp) {
    int gi = blockIdx.x * 256 + threadIdx.x;    // 2,621,440 total
    int bl  = gi & 15;
    int khi = (gi >> 4) & 3;
    int kc  = (gi >> 6) & 7;
    int mt  = (gi >> 9) & 511;
    int t   = gi >> 18;
    int b = mt * 16 + bl;
    int L = lengths[b];
    float pos = ((float)t * (float)(L - 1)) / 9.0f;
    int i0 = (int)pos;
    float f = pos - (float)i0;
    int i1 = min(i0 + 1, L - 1);
    int c0 = words[b * LMAX + i0];
    int c1 = words[b * LMAX + i1];
    const float* p0 = P + c0 * 256 + kc * 32 + khi * 8;
    const float* p1 = P + c1 * 256 + kc * 32 + khi * 8;
    f16x8 r;
#pragma unroll
    for (int j = 0; j < 8; ++j) {
        float v = p0[j] * (1.0f - f) + p1[j] * f;
        v = fmaxf(v, 0.0f);
        r[j] = (f16)v;
    }
    *((f16x8*)seqp + gi) = r;
}

// ---------------------------------------------------------------------------
// K2: fused BiLSTM. 256 blocks (128 fwd + 128 bwd) x 512 thr (8 waves).
// Block owns 64 batch rows; wave tile 64 rows x 128 gate-cols.
// Double-buffered h in LDS (2x32KB) -> ONE barrier per step; hcat write of
// h(t-1) deferred into step t so it overlaps the MFMA phase.
// ---------------------------------------------------------------------------
__global__ __launch_bounds__(512, 2) void lstm_fused(
    const f16* __restrict__ seqp, const f16* __restrict__ Wp,
    const float* __restrict__ bp, f16* __restrict__ hcat) {
    const int dir  = blockIdx.x >> 7;
    const int r0t  = (blockIdx.x & 127) << 2;   // row-tile base, 4 tiles of 16
    const int wave = threadIdx.x >> 6;
    const int lane = threadIdx.x & 63;
    const int l16  = lane & 15;
    const int quad = lane >> 4;

    __shared__ __align__(16) f16 hbuf[2][4 * 8 * 512];   // 2 x 32 KB

    // zero h0 buffer
    {
        f16x8 z = {(f16)0, (f16)0, (f16)0, (f16)0, (f16)0, (f16)0, (f16)0, (f16)0};
        for (int i = threadIdx.x; i < 2048; i += 512) ((f16x8*)hbuf[0])[i] = z;
    }

    // per-lane gate biases (8 n-tiles; nt = gate*2 + us, col = l16)
    const float* bpd = bp + dir * 1024 + wave * 128;
    float bias_l[8];
#pragma unroll
    for (int nt = 0; nt < 8; ++nt) bias_l[nt] = bpd[nt * 16 + l16];

    const f16* Wd = Wp + dir * 524288;

    // precomputed hcat-copy offsets (4 chunks/thread)
    int   csrc[4];
    size_t cdst[4];
#pragma unroll
    for (int r = 0; r < 4; ++r) {
        int i = r * 512 + threadIdx.x;
        int off = i * 8;
        int m  = off >> 12;
        int kc = (off >> 9) & 7;
        int e  = off & 511;
        csrc[r] = off;
        cdst[r] = (size_t)(((r0t + m) * 16 + dir * 8 + kc) * 512 + e);
    }

    float cst[4][4][2];
#pragma unroll
    for (int m = 0; m < 4; ++m)
#pragma unroll
        for (int q = 0; q < 4; ++q) { cst[m][q][0] = 0.0f; cst[m][q][1] = 0.0f; }

    __syncthreads();

    int cur = 0;
    for (int step = 0; step < TOUT; ++step) {
        const int t = dir ? (9 - step) : step;
        const f16* hb_r = hbuf[cur];
        f16*       hb_w = hbuf[cur ^ 1];

        f32x4 acc[4][8];
#pragma unroll
        for (int m = 0; m < 4; ++m)
#pragma unroll
            for (int nt = 0; nt < 8; ++nt)
#pragma unroll
                for (int q = 0; q < 4; ++q) acc[m][nt][q] = bias_l[nt];

        const f16* seqt = seqp + (size_t)(t * 512 + r0t) * 4096;

        // K chunks 0..15: A from seq (global, frag-packed) then h (LDS)
#pragma unroll
        for (int kc = 0; kc < 16; ++kc) {
            f16x8 bfrag[8];
#pragma unroll
            for (int nt = 0; nt < 8; ++nt)
                bfrag[nt] = *(const f16x8*)(Wd + ((kc * 64 + wave * 8 + nt) * 512 + lane * 8));
            f16x8 afrag[4];
            if (kc < 8) {
#pragma unroll
                for (int m = 0; m < 4; ++m)
                    afrag[m] = *(const f16x8*)(seqt + ((m * 8 + kc) * 512 + lane * 8));
            } else {
#pragma unroll
                for (int m = 0; m < 4; ++m)
                    afrag[m] = *(const f16x8*)(hb_r + ((m * 8 + (kc - 8)) * 512 + lane * 8));
            }
#pragma unroll
            for (int m = 0; m < 4; ++m)
#pragma unroll
                for (int nt = 0; nt < 8; ++nt)
                    acc[m][nt] = __builtin_amdgcn_mfma_f32_16x16x32_f16(
                        afrag[m], bfrag[nt], acc[m][nt], 0, 0, 0);
        }

        // deferred hcat write of h(t_prev) from hb_r — overlaps MFMA drain
        if (step > 0) {
            const int tp = dir ? (t + 1) : (t - 1);
            const size_t tb = (size_t)tp * 4194304;
#pragma unroll
            for (int r = 0; r < 4; ++r)
                *(f16x8*)(hcat + tb + cdst[r]) = *(const f16x8*)(hb_r + csrc[r]);
        }

        // lane-local gate combine; packed b32 h-store into hb_w.
        // nt = gate*2+us; lane's units: u0=2*l16 (us=0), u1=2*l16+1 (us=1)
#pragma unroll
        for (int m = 0; m < 4; ++m) {
#pragma unroll
            for (int q = 0; q < 4; ++q) {
                float i0 = acc[m][0][q], i1 = acc[m][1][q];
                float f0 = acc[m][2][q], f1 = acc[m][3][q];
                float g0 = acc[m][4][q], g1 = acc[m][5][q];
                float o0 = acc[m][6][q], o1 = acc[m][7][q];
                float c0 = sigm_(f0) * cst[m][q][0] + sigm_(i0) * tanh_(g0);
                float c1 = sigm_(f1) * cst[m][q][1] + sigm_(i1) * tanh_(g1);
                cst[m][q][0] = c0;
                cst[m][q][1] = c1;
                float h0 = sigm_(o0) * tanh_(c0);
                float h1 = sigm_(o1) * tanh_(c1);
                f16x2 hv = pk_f16(h0, h1);
                *(f16x2*)&hb_w[(m * 8 + wave) * 512 +
                               ((l16 >> 2) * 16 + quad * 4 + q) * 8 + 2 * (l16 & 3)] = hv;
            }
        }

        __syncthreads();   // single barrier per step
        cur ^= 1;
    }

    // final h(t_last) write
    {
        const int tl = dir ? 0 : 9;
        const size_t tb = (size_t)tl * 4194304;
        const f16* hb_r = hbuf[cur];
#pragma unroll
        for (int r = 0; r < 4; ++r)
            *(f16x8*)(hcat + tb + cdst[r]) = *(const f16x8*)(hb_r + csrc[r]);
    }
}

// ---------------------------------------------------------------------------
// K3: out = h_cat(81920x512 f16, frag layout) @ W3p + out_b -> fp32 (B,10,512)
// 640 blocks x 512 thr; block tile 128 rows x 512 cols; wave: 128x64.
// ---------------------------------------------------------------------------
__global__ __launch_bounds__(512, 2) void out_gemm(
    const f16* __restrict__ hcat, const f16* __restrict__ W3p,
    const float* __restrict__ out_b, float* __restrict__ out) {
    const int mt0  = blockIdx.x << 3;
    const int wave = threadIdx.x >> 6;
    const int lane = threadIdx.x & 63;
    const int l16  = lane & 15;
    const int quad = lane >> 4;
    const int n0   = wave * 64;

    float bias_l[4];
#pragma unroll
    for (int nt = 0; nt < 4; ++nt) bias_l[nt] = out_b[n0 + nt * 16 + l16];

    f32x4 acc[8][4];
#pragma unroll
    for (int m = 0; m < 8; ++m)
#pragma unroll
        for (int nt = 0; nt < 4; ++nt)
#pragma unroll
            for (int q = 0; q < 4; ++q) acc[m][nt][q] = bias_l[nt];

#pragma unroll 4
    for (int kc = 0; kc < 16; ++kc) {
        f16x8 b[4];
#pragma unroll
        for (int nt = 0; nt < 4; ++nt)
            b[nt] = *(const f16x8*)(W3p + ((kc * 32 + wave * 4 + nt) * 512 + lane * 8));
        f16x8 a[8];
#pragma unroll
        for (int m = 0; m < 8; ++m)
            a[m] = *(const f16x8*)(hcat + ((size_t)((mt0 + m) * 16 + kc) * 512 + lane * 8));
#pragma unroll
        for (int m = 0; m < 8; ++m)
#pragma unroll
            for (int nt = 0; nt < 4; ++nt)
                acc[m][nt] = __builtin_amdgcn_mfma_f32_16x16x32_f16(a[m], b[nt], acc[m][nt], 0, 0, 0);
    }

#pragma unroll
    for (int m = 0; m < 8; ++m) {
#pragma unroll
        for (int nt = 0; nt < 4; ++nt) {
#pragma unroll
            for (int q = 0; q < 4; ++q) {
                int R = (mt0 + m) * 16 + quad * 4 + q;
                int t = R >> 13;
                int b = R & 8191;
                out[(size_t)(b * 10 + t) * 512 + n0 + nt * 16 + l16] = acc[m][nt][q];
            }
        }
    }
}

// ---------------------------------------------------------------------------
extern "C" void kernel_launch(void* const* d_in, const int* in_sizes, int n_in,
                              void* d_out, int out_size, void* d_ws, size_t ws_size,
                              hipStream_t stream) {
    const int*   words   = (const int*)d_in[0];
    const int*   lengths = (const int*)d_in[1];
    const float* tab     = (const float*)d_in[2];
    const float* enc_w   = (const float*)d_in[3];
    const float* enc_b   = (const float*)d_in[4];
    const float* wih_f   = (const float*)d_in[5];
    const float* whh_f   = (const float*)d_in[6];
    const float* bih_f   = (const float*)d_in[7];
    const float* bhh_f   = (const float*)d_in[8];
    const float* wih_b   = (const float*)d_in[9];
    const float* whh_b   = (const float*)d_in[10];
    const float* bih_b   = (const float*)d_in[11];
    const float* bhh_b   = (const float*)d_in[12];
    const float* out_w   = (const float*)d_in[13];
    const float* out_b   = (const float*)d_in[14];
    float* out = (float*)d_out;

    char* ws = (char*)d_ws;
    f16*   Wp   = (f16*)(ws + 0);           //  2 MB
    f16*   W3p  = (f16*)(ws + 2097152);     //  0.5 MB
    float* bp   = (float*)(ws + 2621440);   //  8 KB
    float* P    = (float*)(ws + 2629632);   //  36 KB
    f16*   seqp = (f16*)(ws + 2666496);     //  40 MB
    f16*   hcat = (f16*)(ws + 44609536);    //  80 MB  (total ~122.6 MB)

    pack_w2<<<4096, 256, 0, stream>>>(wih_f, whh_f, wih_b, whh_b, Wp);
    pack_bias<<<8, 256, 0, stream>>>(bih_f, bhh_f, bih_b, bhh_b, bp);
    pack_w3<<<1024, 256, 0, stream>>>(out_w, W3p);
    enc_proj<<<36, 256, 0, stream>>>(tab, enc_w, enc_b, P);
    build_seq<<<10240, 256, 0, stream>>>(words, lengths, P, seqp);
    lstm_fused<<<256, 512, 0, stream>>>(seqp, Wp, bp, hcat);
    out_gemm<<<640, 512, 0, stream>>>(hcat, W3p, out_b, out);
}

// Round 4
// 513.665 us; speedup vs baseline: 2.3869x; 2.3869x over previous
//
#include <hip/hip_runtime.h>
#include <hip/hip_fp16.h>

typedef _Float16 f16;
typedef _Float16 f16x2 __attribute__((ext_vector_type(2)));
typedef _Float16 f16x8 __attribute__((ext_vector_type(8)));
typedef float    f32x4 __attribute__((ext_vector_type(4)));

#define NB   8192
#define TOUT 10
#define LMAX 12
#define EMB  300

__device__ __forceinline__ float sigm_(float x) {
    return __builtin_amdgcn_rcpf(1.0f + __builtin_amdgcn_exp2f(x * -1.44269504f));
}
__device__ __forceinline__ float tanh_(float x) {
    return 1.0f - 2.0f * __builtin_amdgcn_rcpf(1.0f + __builtin_amdgcn_exp2f(x * 2.88539008f));
}
__device__ __forceinline__ f16x2 pk_f16(float a, float b) {
    return __builtin_bit_cast(f16x2, __builtin_amdgcn_cvt_pkrtz(a, b));
}

// ---------------------------------------------------------------------------
// K0a: pack LSTM weights into MFMA B-fragment tiles, f16, gate-permuted cols.
// Dest per dir: [kc 0..15][ntile 0..63][512 f16]; within tile element (k,n):
// offset = ((k%32)/8*16 + n%16)*8 + k%8 (lane l reads l*8..l*8+7).
// Column permutation: n -> w=n/128, rr=n%128, gate=rr>>5, us=(rr>>4)&1,
// l16=rr&15, unit u = w*32 + 2*l16 + us  (lane's us=0/1 values LDS-adjacent).
// ---------------------------------------------------------------------------
__global__ __launch_bounds__(256) void pack_w2(
    const float* __restrict__ wih_f, const float* __restrict__ whh_f,
    const float* __restrict__ wih_b, const float* __restrict__ whh_b,
    f16* __restrict__ Wp) {
    int idx = blockIdx.x * 256 + threadIdx.x;   // 0 .. 2*524288-1
    int d   = idx >> 19;
    int r   = idx & 524287;
    int tile = r >> 9;
    int e    = r & 511;
    int kc = tile >> 6, nt = tile & 63;
    int khi = e >> 7, rem = e & 127, nl = rem >> 3, klo = rem & 7;
    int n = nt * 16 + nl;
    int k = kc * 32 + khi * 8 + klo;
    int w = n >> 7, rr = n & 127, gate = rr >> 5;
    int u = w * 32 + 2 * (rr & 15) + ((rr >> 4) & 1);
    int srow = gate * 256 + u;
    const float* wih = d ? wih_b : wih_f;
    const float* whh = d ? whh_b : whh_f;
    float v = (k < 256) ? wih[srow * 256 + k] : whh[srow * 256 + (k - 256)];
    Wp[idx] = (f16)v;
}

__global__ __launch_bounds__(256) void pack_bias(
    const float* __restrict__ bih_f, const float* __restrict__ bhh_f,
    const float* __restrict__ bih_b, const float* __restrict__ bhh_b,
    float* __restrict__ bp) {
    int idx = blockIdx.x * 256 + threadIdx.x;   // 2048
    int d = idx >> 10, n = idx & 1023;
    int w = n >> 7, rr = n & 127, gate = rr >> 5;
    int u = w * 32 + 2 * (rr & 15) + ((rr >> 4) & 1);
    int srow = gate * 256 + u;
    bp[idx] = d ? (bih_b[srow] + bhh_b[srow]) : (bih_f[srow] + bhh_f[srow]);
}

// K0b: pack out_w (512x512) into B-fragment tiles: [kc 0..15][ntile 0..31][512]
__global__ __launch_bounds__(256) void pack_w3(
    const float* __restrict__ out_w, f16* __restrict__ W3p) {
    int idx = blockIdx.x * 256 + threadIdx.x;   // 262144
    int tile = idx >> 9, e = idx & 511;
    int kc = tile >> 5, nt = tile & 31;
    int khi = e >> 7, rem = e & 127, nl = rem >> 3, klo = rem & 7;
    int n = nt * 16 + nl, k = kc * 32 + khi * 8 + klo;
    W3p[idx] = (f16)out_w[n * 512 + k];
}

// K0c: P[36][256] = emb_table @ enc_w^T + enc_b (fp32)
__global__ __launch_bounds__(256) void enc_proj(
    const float* __restrict__ tab, const float* __restrict__ ew,
    const float* __restrict__ eb, float* __restrict__ P) {
    int v = blockIdx.x, j = threadIdx.x;
    const float* a = tab + v * EMB;
    const float* w = ew + j * EMB;
    float s = 0.0f;
    for (int k = 0; k < EMB; ++k) s += a[k] * w[k];
    P[v * 256 + j] = s + eb[j];
}

// ---------------------------------------------------------------------------
// K1: build seq in MFMA A-fragment tile layout, f16.
// seqp: [t 0..9][mtile 0..511][kc 0..7][512 f16]; element (row,k):
// offset = ((k%32)/8*16 + row%16)*8 + k%8
// ---------------------------------------------------------------------------
__global__ __launch_bounds__(256) void build_seq(
    const int* __restrict__ words, const int* __restrict__ lengths,
    const float* __restrict__ P, f16* __restrict__ seqp) {
    int gi = blockIdx.x * 256 + threadIdx.x;    // 2,621,440 total
    int bl  = gi & 15;
    int khi = (gi >> 4) & 3;
    int kc  = (gi >> 6) & 7;
    int mt  = (gi >> 9) & 511;
    int t   = gi >> 18;
    int b = mt * 16 + bl;
    int L = lengths[b];
    float pos = ((float)t * (float)(L - 1)) / 9.0f;
    int i0 = (int)pos;
    float f = pos - (float)i0;
    int i1 = min(i0 + 1, L - 1);
    int c0 = words[b * LMAX + i0];
    int c1 = words[b * LMAX + i1];
    const float* p0 = P + c0 * 256 + kc * 32 + khi * 8;
    const float* p1 = P + c1 * 256 + kc * 32 + khi * 8;
    f16x8 r;
#pragma unroll
    for (int j = 0; j < 8; ++j) {
        float v = p0[j] * (1.0f - f) + p1[j] * f;
        v = fmaxf(v, 0.0f);
        r[j] = (f16)v;
    }
    *((f16x8*)seqp + gi) = r;
}

// ---------------------------------------------------------------------------
// K2: fused BiLSTM. 256 blocks (128 fwd + 128 bwd) x 512 thr (8 waves).
// Block owns 64 batch rows; wave tile 64 rows x 128 gate-cols.
// Double-buffered h (2x32KB LDS) -> ONE barrier per step; hcat write of
// h(t-1) deferred into step t. K-loop kept as two 8-iter halves with
// unroll 2 — round 2 showed full unroll blows the 128-VGPR budget and
// spills ~2 GB of scratch to HBM.
// ---------------------------------------------------------------------------
__global__ __launch_bounds__(512) void lstm_fused(
    const f16* __restrict__ seqp, const f16* __restrict__ Wp,
    const float* __restrict__ bp, f16* __restrict__ hcat) {
    const int dir  = blockIdx.x >> 7;
    const int r0t  = (blockIdx.x & 127) << 2;   // row-tile base, 4 tiles of 16
    const int wave = threadIdx.x >> 6;
    const int lane = threadIdx.x & 63;
    const int l16  = lane & 15;
    const int quad = lane >> 4;

    __shared__ __align__(16) f16 hbuf[2][4 * 8 * 512];   // 2 x 32 KB

    // zero h0 buffer
    {
        f16x8 z = {(f16)0, (f16)0, (f16)0, (f16)0, (f16)0, (f16)0, (f16)0, (f16)0};
        for (int i = threadIdx.x; i < 2048; i += 512) ((f16x8*)hbuf[0])[i] = z;
    }

    // per-lane gate biases (8 n-tiles; nt = gate*2 + us, col = l16)
    const float* bpd = bp + dir * 1024 + wave * 128;
    float bias_l[8];
#pragma unroll
    for (int nt = 0; nt < 8; ++nt) bias_l[nt] = bpd[nt * 16 + l16];

    const f16* Wd = Wp + dir * 524288;

    // precomputed hcat-copy offsets (4 chunks/thread)
    int   csrc[4];
    size_t cdst[4];
#pragma unroll
    for (int r = 0; r < 4; ++r) {
        int i = r * 512 + threadIdx.x;
        int off = i * 8;
        int m  = off >> 12;
        int kc = (off >> 9) & 7;
        int e  = off & 511;
        csrc[r] = off;
        cdst[r] = (size_t)(((r0t + m) * 16 + dir * 8 + kc) * 512 + e);
    }

    float cst[4][4][2];
#pragma unroll
    for (int m = 0; m < 4; ++m)
#pragma unroll
        for (int q = 0; q < 4; ++q) { cst[m][q][0] = 0.0f; cst[m][q][1] = 0.0f; }

    __syncthreads();

    int cur = 0;
    for (int step = 0; step < TOUT; ++step) {
        const int t = dir ? (9 - step) : step;
        const f16* hb_r = hbuf[cur];
        f16*       hb_w = hbuf[cur ^ 1];

        f32x4 acc[4][8];
#pragma unroll
        for (int m = 0; m < 4; ++m)
#pragma unroll
            for (int nt = 0; nt < 8; ++nt)
#pragma unroll
                for (int q = 0; q < 4; ++q) acc[m][nt][q] = bias_l[nt];

        const f16* seqt = seqp + (size_t)(t * 512 + r0t) * 4096;

        // K chunks 0..7: A from seq (global, fragment-packed)
#pragma unroll 2
        for (int kc = 0; kc < 8; ++kc) {
            f16x8 bfrag[8];
#pragma unroll
            for (int nt = 0; nt < 8; ++nt)
                bfrag[nt] = *(const f16x8*)(Wd + ((kc * 64 + wave * 8 + nt) * 512 + lane * 8));
            f16x8 afrag[4];
#pragma unroll
            for (int m = 0; m < 4; ++m)
                afrag[m] = *(const f16x8*)(seqt + ((m * 8 + kc) * 512 + lane * 8));
#pragma unroll
            for (int m = 0; m < 4; ++m)
#pragma unroll
                for (int nt = 0; nt < 8; ++nt)
                    acc[m][nt] = __builtin_amdgcn_mfma_f32_16x16x32_f16(
                        afrag[m], bfrag[nt], acc[m][nt], 0, 0, 0);
        }
        // K chunks 8..15: A = h (LDS, fragment-packed)
#pragma unroll 2
        for (int kcl = 0; kcl < 8; ++kcl) {
            int kc = kcl + 8;
            f16x8 bfrag[8];
#pragma unroll
            for (int nt = 0; nt < 8; ++nt)
                bfrag[nt] = *(const f16x8*)(Wd + ((kc * 64 + wave * 8 + nt) * 512 + lane * 8));
            f16x8 afrag[4];
#pragma unroll
            for (int m = 0; m < 4; ++m)
                afrag[m] = *(const f16x8*)(hb_r + ((m * 8 + kcl) * 512 + lane * 8));
#pragma unroll
            for (int m = 0; m < 4; ++m)
#pragma unroll
                for (int nt = 0; nt < 8; ++nt)
                    acc[m][nt] = __builtin_amdgcn_mfma_f32_16x16x32_f16(
                        afrag[m], bfrag[nt], acc[m][nt], 0, 0, 0);
        }

        // deferred hcat write of h(t_prev) from hb_r — overlaps MFMA drain
        if (step > 0) {
            const int tp = dir ? (t + 1) : (t - 1);
            const size_t tb = (size_t)tp * 4194304;
#pragma unroll
            for (int r = 0; r < 4; ++r)
                *(f16x8*)(hcat + tb + cdst[r]) = *(const f16x8*)(hb_r + csrc[r]);
        }

        // lane-local gate combine; packed b32 h-store into hb_w.
        // nt = gate*2+us; lane's units: u0=2*l16 (us=0), u1=2*l16+1 (us=1)
#pragma unroll
        for (int m = 0; m < 4; ++m) {
#pragma unroll
            for (int q = 0; q < 4; ++q) {
                float i0 = acc[m][0][q], i1 = acc[m][1][q];
                float f0 = acc[m][2][q], f1 = acc[m][3][q];
                float g0 = acc[m][4][q], g1 = acc[m][5][q];
                float o0 = acc[m][6][q], o1 = acc[m][7][q];
                float c0 = sigm_(f0) * cst[m][q][0] + sigm_(i0) * tanh_(g0);
                float c1 = sigm_(f1) * cst[m][q][1] + sigm_(i1) * tanh_(g1);
                cst[m][q][0] = c0;
                cst[m][q][1] = c1;
                float h0 = sigm_(o0) * tanh_(c0);
                float h1 = sigm_(o1) * tanh_(c1);
                f16x2 hv = pk_f16(h0, h1);
                *(f16x2*)&hb_w[(m * 8 + wave) * 512 +
                               ((l16 >> 2) * 16 + quad * 4 + q) * 8 + 2 * (l16 & 3)] = hv;
            }
        }

        __syncthreads();   // single barrier per step
        cur ^= 1;
    }

    // final h(t_last) write
    {
        const int tl = dir ? 0 : 9;
        const size_t tb = (size_t)tl * 4194304;
        const f16* hb_r = hbuf[cur];
#pragma unroll
        for (int r = 0; r < 4; ++r)
            *(f16x8*)(hcat + tb + cdst[r]) = *(const f16x8*)(hb_r + csrc[r]);
    }
}

// ---------------------------------------------------------------------------
// K3: out = h_cat(81920x512 f16, frag layout) @ W3p + out_b -> fp32 (B,10,512)
// 1280 blocks x 512 thr; block tile 64 rows x 512 cols; wave: 64x64.
// (128-row variant spilled under the register budget — keep 64.)
// ---------------------------------------------------------------------------
__global__ __launch_bounds__(512) void out_gemm(
    const f16* __restrict__ hcat, const f16* __restrict__ W3p,
    const float* __restrict__ out_b, float* __restrict__ out) {
    const int mt0  = blockIdx.x << 2;
    const int wave = threadIdx.x >> 6;
    const int lane = threadIdx.x & 63;
    const int l16  = lane & 15;
    const int quad = lane >> 4;
    const int n0   = wave * 64;

    float bias_l[4];
#pragma unroll
    for (int nt = 0; nt < 4; ++nt) bias_l[nt] = out_b[n0 + nt * 16 + l16];

    f32x4 acc[4][4];
#pragma unroll
    for (int m = 0; m < 4; ++m)
#pragma unroll
        for (int nt = 0; nt < 4; ++nt)
#pragma unroll
            for (int q = 0; q < 4; ++q) acc[m][nt][q] = bias_l[nt];

#pragma unroll 2
    for (int kc = 0; kc < 16; ++kc) {
        f16x8 a[4], b[4];
#pragma unroll
        for (int m = 0; m < 4; ++m)
            a[m] = *(const f16x8*)(hcat + ((size_t)((mt0 + m) * 16 + kc) * 512 + lane * 8));
#pragma unroll
        for (int nt = 0; nt < 4; ++nt)
            b[nt] = *(const f16x8*)(W3p + ((kc * 32 + wave * 4 + nt) * 512 + lane * 8));
#pragma unroll
        for (int m = 0; m < 4; ++m)
#pragma unroll
            for (int nt = 0; nt < 4; ++nt)
                acc[m][nt] = __builtin_amdgcn_mfma_f32_16x16x32_f16(a[m], b[nt], acc[m][nt], 0, 0, 0);
    }

#pragma unroll
    for (int m = 0; m < 4; ++m) {
#pragma unroll
        for (int nt = 0; nt < 4; ++nt) {
#pragma unroll
            for (int q = 0; q < 4; ++q) {
                int R = mt0 * 16 + m * 16 + quad * 4 + q;
                int t = R >> 13;
                int b = R & 8191;
                out[(size_t)(b * 10 + t) * 512 + n0 + nt * 16 + l16] = acc[m][nt][q];
            }
        }
    }
}

// ---------------------------------------------------------------------------
extern "C" void kernel_launch(void* const* d_in, const int* in_sizes, int n_in,
                              void* d_out, int out_size, void* d_ws, size_t ws_size,
                              hipStream_t stream) {
    const int*   words   = (const int*)d_in[0];
    const int*   lengths = (const int*)d_in[1];
    const float* tab     = (const float*)d_in[2];
    const float* enc_w   = (const float*)d_in[3];
    const float* enc_b   = (const float*)d_in[4];
    const float* wih_f   = (const float*)d_in[5];
    const float* whh_f   = (const float*)d_in[6];
    const float* bih_f   = (const float*)d_in[7];
    const float* bhh_f   = (const float*)d_in[8];
    const float* wih_b   = (const float*)d_in[9];
    const float* whh_b   = (const float*)d_in[10];
    const float* bih_b   = (const float*)d_in[11];
    const float* bhh_b   = (const float*)d_in[12];
    const float* out_w   = (const float*)d_in[13];
    const float* out_b   = (const float*)d_in[14];
    float* out = (float*)d_out;

    char* ws = (char*)d_ws;
    f16*   Wp   = (f16*)(ws + 0);           //  2 MB
    f16*   W3p  = (f16*)(ws + 2097152);     //  0.5 MB
    float* bp   = (float*)(ws + 2621440);   //  8 KB
    float* P    = (float*)(ws + 2629632);   //  36 KB
    f16*   seqp = (f16*)(ws + 2666496);     //  40 MB
    f16*   hcat = (f16*)(ws + 44609536);    //  80 MB  (total ~122.6 MB)

    pack_w2<<<4096, 256, 0, stream>>>(wih_f, whh_f, wih_b, whh_b, Wp);
    pack_bias<<<8, 256, 0, stream>>>(bih_f, bhh_f, bih_b, bhh_b, bp);
    pack_w3<<<1024, 256, 0, stream>>>(out_w, W3p);
    enc_proj<<<36, 256, 0, stream>>>(tab, enc_w, enc_b, P);
    build_seq<<<10240, 256, 0, stream>>>(words, lengths, P, seqp);
    lstm_fused<<<256, 512, 0, stream>>>(seqp, Wp, bp, hcat);
    out_gemm<<<1280, 512, 0, stream>>>(hcat, W3p, out_b, out);
}

// Round 5
// 477.476 us; speedup vs baseline: 2.5678x; 1.0758x over previous
//
#include <hip/hip_runtime.h>
#include <hip/hip_fp16.h>

typedef _Float16 f16;
typedef _Float16 f16x2 __attribute__((ext_vector_type(2)));
typedef _Float16 f16x8 __attribute__((ext_vector_type(8)));
typedef float    f32x4 __attribute__((ext_vector_type(4)));

#define NB   8192
#define TOUT 10
#define LMAX 12
#define EMB  300

__device__ __forceinline__ float sigm_(float x) {
    return __builtin_amdgcn_rcpf(1.0f + __builtin_amdgcn_exp2f(x * -1.44269504f));
}
__device__ __forceinline__ float tanh_(float x) {
    return 1.0f - 2.0f * __builtin_amdgcn_rcpf(1.0f + __builtin_amdgcn_exp2f(x * 2.88539008f));
}
__device__ __forceinline__ f16x2 pk_f16(float a, float b) {
    return __builtin_bit_cast(f16x2, __builtin_amdgcn_cvt_pkrtz(a, b));
}

// ---------------------------------------------------------------------------
// K0a: pack LSTM weights into MFMA B-fragment tiles, f16, gate-permuted cols.
// Dest per dir: [kc 0..15][ntile 0..63][512 f16]; within tile element (k,n):
// offset = ((k%32)/8*16 + n%16)*8 + k%8 (lane l reads l*8..l*8+7).
// Column permutation: n -> w=n/128, rr=n%128, gate=rr>>5, us=(rr>>4)&1,
// l16=rr&15, unit u = w*32 + 2*l16 + us.
// ---------------------------------------------------------------------------
__global__ __launch_bounds__(256) void pack_w2(
    const float* __restrict__ wih_f, const float* __restrict__ whh_f,
    const float* __restrict__ wih_b, const float* __restrict__ whh_b,
    f16* __restrict__ Wp) {
    int idx = blockIdx.x * 256 + threadIdx.x;   // 0 .. 2*524288-1
    int d   = idx >> 19;
    int r   = idx & 524287;
    int tile = r >> 9;
    int e    = r & 511;
    int kc = tile >> 6, nt = tile & 63;
    int khi = e >> 7, rem = e & 127, nl = rem >> 3, klo = rem & 7;
    int n = nt * 16 + nl;
    int k = kc * 32 + khi * 8 + klo;
    int w = n >> 7, rr = n & 127, gate = rr >> 5;
    int u = w * 32 + 2 * (rr & 15) + ((rr >> 4) & 1);
    int srow = gate * 256 + u;
    const float* wih = d ? wih_b : wih_f;
    const float* whh = d ? whh_b : whh_f;
    float v = (k < 256) ? wih[srow * 256 + k] : whh[srow * 256 + (k - 256)];
    Wp[idx] = (f16)v;
}

__global__ __launch_bounds__(256) void pack_bias(
    const float* __restrict__ bih_f, const float* __restrict__ bhh_f,
    const float* __restrict__ bih_b, const float* __restrict__ bhh_b,
    float* __restrict__ bp) {
    int idx = blockIdx.x * 256 + threadIdx.x;   // 2048
    int d = idx >> 10, n = idx & 1023;
    int w = n >> 7, rr = n & 127, gate = rr >> 5;
    int u = w * 32 + 2 * (rr & 15) + ((rr >> 4) & 1);
    int srow = gate * 256 + u;
    bp[idx] = d ? (bih_b[srow] + bhh_b[srow]) : (bih_f[srow] + bhh_f[srow]);
}

// K0b: pack out_w (512x512) into B-fragment tiles: [kc 0..15][ntile 0..31][512]
__global__ __launch_bounds__(256) void pack_w3(
    const float* __restrict__ out_w, f16* __restrict__ W3p) {
    int idx = blockIdx.x * 256 + threadIdx.x;   // 262144
    int tile = idx >> 9, e = idx & 511;
    int kc = tile >> 5, nt = tile & 31;
    int khi = e >> 7, rem = e & 127, nl = rem >> 3, klo = rem & 7;
    int n = nt * 16 + nl, k = kc * 32 + khi * 8 + klo;
    W3p[idx] = (f16)out_w[n * 512 + k];
}

// K0c: P[36][256] = emb_table @ enc_w^T + enc_b (fp32)
__global__ __launch_bounds__(256) void enc_proj(
    const float* __restrict__ tab, const float* __restrict__ ew,
    const float* __restrict__ eb, float* __restrict__ P) {
    int v = blockIdx.x, j = threadIdx.x;
    const float* a = tab + v * EMB;
    const float* w = ew + j * EMB;
    float s = 0.0f;
    for (int k = 0; k < EMB; ++k) s += a[k] * w[k];
    P[v * 256 + j] = s + eb[j];
}

// ---------------------------------------------------------------------------
// K1: build seq in MFMA A-fragment tile layout, f16.
// seqp: [t 0..9][mtile 0..511][kc 0..7][512 f16]; element (row,k):
// offset = ((k%32)/8*16 + row%16)*8 + k%8
// ---------------------------------------------------------------------------
__global__ __launch_bounds__(256) void build_seq(
    const int* __restrict__ words, const int* __restrict__ lengths,
    const float* __restrict__ P, f16* __restrict__ seqp) {
    int gi = blockIdx.x * 256 + threadIdx.x;    // 2,621,440 total
    int bl  = gi & 15;
    int khi = (gi >> 4) & 3;
    int kc  = (gi >> 6) & 7;
    int mt  = (gi >> 9) & 511;
    int t   = gi >> 18;
    int b = mt * 16 + bl;
    int L = lengths[b];
    float pos = ((float)t * (float)(L - 1)) / 9.0f;
    int i0 = (int)pos;
    float f = pos - (float)i0;
    int i1 = min(i0 + 1, L - 1);
    int c0 = words[b * LMAX + i0];
    int c1 = words[b * LMAX + i1];
    const float* p0 = P + c0 * 256 + kc * 32 + khi * 8;
    const float* p1 = P + c1 * 256 + kc * 32 + khi * 8;
    f16x8 r;
#pragma unroll
    for (int j = 0; j < 8; ++j) {
        float v = p0[j] * (1.0f - f) + p1[j] * f;
        v = fmaxf(v, 0.0f);
        r[j] = (f16)v;
    }
    *((f16x8*)seqp + gi) = r;
}

// ---------------------------------------------------------------------------
// K2: fused BiLSTM. 256 blocks (128 fwd + 128 bwd) x 512 thr (8 waves).
// Block owns 64 batch rows; wave tile 64 rows x 128 gate-cols.
// Double-buffered h (2x32KB LDS), ONE barrier per step. h is written
// DIRECTLY to global hcat from the combine registers (f16x2 stores) —
// no LDS round-trip, no deferred-copy live ranges (round-4 spill cause).
// ---------------------------------------------------------------------------
__global__ __launch_bounds__(512) void lstm_fused(
    const f16* __restrict__ seqp, const f16* __restrict__ Wp,
    const float* __restrict__ bp, f16* __restrict__ hcat) {
    const int dir  = blockIdx.x >> 7;
    const int r0t  = (blockIdx.x & 127) << 2;   // row-tile base, 4 tiles of 16
    const int wave = threadIdx.x >> 6;
    const int lane = threadIdx.x & 63;
    const int l16  = lane & 15;
    const int quad = lane >> 4;

    __shared__ __align__(16) f16 hbuf[2][4 * 8 * 512];   // 2 x 32 KB

    // zero h0 buffer
    {
        f16x8 z = {(f16)0, (f16)0, (f16)0, (f16)0, (f16)0, (f16)0, (f16)0, (f16)0};
        for (int i = threadIdx.x; i < 2048; i += 512) ((f16x8*)hbuf[0])[i] = z;
    }

    // per-lane gate biases (8 n-tiles; nt = gate*2 + us, col = l16)
    const float* bpd = bp + dir * 1024 + wave * 128;
    float bias_l[8];
#pragma unroll
    for (int nt = 0; nt < 8; ++nt) bias_l[nt] = bpd[nt * 16 + l16];

    const f16* Wd = Wp + dir * 524288;

    // within-tile offset for this lane's h (same for LDS and global stores):
    // wt = ((l16>>2)*16 + quad*4 + q)*8 + 2*(l16&3)
    const int wt0 = ((l16 >> 2) * 16 + quad * 4) * 8 + 2 * (l16 & 3);
    // global tile base: ((t*512 + r0t + m)*16 + dir*8 + wave)*512
    const int tile_lo = (r0t * 16 + dir * 8 + wave) * 512;

    float cst[4][4][2];
#pragma unroll
    for (int m = 0; m < 4; ++m)
#pragma unroll
        for (int q = 0; q < 4; ++q) { cst[m][q][0] = 0.0f; cst[m][q][1] = 0.0f; }

    __syncthreads();

    int cur = 0;
#pragma unroll 1
    for (int step = 0; step < TOUT; ++step) {
        const int t = dir ? (9 - step) : step;
        const f16* hb_r = hbuf[cur];
        f16*       hb_w = hbuf[cur ^ 1];

        f32x4 acc[4][8];
#pragma unroll
        for (int m = 0; m < 4; ++m)
#pragma unroll
            for (int nt = 0; nt < 8; ++nt)
#pragma unroll
                for (int q = 0; q < 4; ++q) acc[m][nt][q] = bias_l[nt];

        const f16* seqt = seqp + (size_t)(t * 512 + r0t) * 4096;

        // K chunks 0..7: A from seq (global, fragment-packed)
#pragma unroll 2
        for (int kc = 0; kc < 8; ++kc) {
            f16x8 bfrag[8];
#pragma unroll
            for (int nt = 0; nt < 8; ++nt)
                bfrag[nt] = *(const f16x8*)(Wd + ((kc * 64 + wave * 8 + nt) * 512 + lane * 8));
            f16x8 afrag[4];
#pragma unroll
            for (int m = 0; m < 4; ++m)
                afrag[m] = *(const f16x8*)(seqt + ((m * 8 + kc) * 512 + lane * 8));
#pragma unroll
            for (int m = 0; m < 4; ++m)
#pragma unroll
                for (int nt = 0; nt < 8; ++nt)
                    acc[m][nt] = __builtin_amdgcn_mfma_f32_16x16x32_f16(
                        afrag[m], bfrag[nt], acc[m][nt], 0, 0, 0);
        }
        // K chunks 8..15: A = h (LDS, fragment-packed)
#pragma unroll 2
        for (int kcl = 0; kcl < 8; ++kcl) {
            int kc = kcl + 8;
            f16x8 bfrag[8];
#pragma unroll
            for (int nt = 0; nt < 8; ++nt)
                bfrag[nt] = *(const f16x8*)(Wd + ((kc * 64 + wave * 8 + nt) * 512 + lane * 8));
            f16x8 afrag[4];
#pragma unroll
            for (int m = 0; m < 4; ++m)
                afrag[m] = *(const f16x8*)(hb_r + ((m * 8 + kcl) * 512 + lane * 8));
#pragma unroll
            for (int m = 0; m < 4; ++m)
#pragma unroll
                for (int nt = 0; nt < 8; ++nt)
                    acc[m][nt] = __builtin_amdgcn_mfma_f32_16x16x32_f16(
                        afrag[m], bfrag[nt], acc[m][nt], 0, 0, 0);
        }

        // lane-local gate combine; h -> LDS (for recurrence) + global hcat
        f16* hct = hcat + ((size_t)t * 4194304 + tile_lo);
#pragma unroll
        for (int m = 0; m < 4; ++m) {
#pragma unroll
            for (int q = 0; q < 4; ++q) {
                float i0 = acc[m][0][q], i1 = acc[m][1][q];
                float f0 = acc[m][2][q], f1 = acc[m][3][q];
                float g0 = acc[m][4][q], g1 = acc[m][5][q];
                float o0 = acc[m][6][q], o1 = acc[m][7][q];
                float c0 = sigm_(f0) * cst[m][q][0] + sigm_(i0) * tanh_(g0);
                float c1 = sigm_(f1) * cst[m][q][1] + sigm_(i1) * tanh_(g1);
                cst[m][q][0] = c0;
                cst[m][q][1] = c1;
                float h0 = sigm_(o0) * tanh_(c0);
                float h1 = sigm_(o1) * tanh_(c1);
                f16x2 hv = pk_f16(h0, h1);
                int wt = wt0 + q * 8;
                *(f16x2*)&hb_w[(m * 8 + wave) * 512 + wt] = hv;
                *(f16x2*)(hct + m * 8192 + wt) = hv;
            }
        }

        __syncthreads();   // single barrier per step
        cur ^= 1;
    }
}

// ---------------------------------------------------------------------------
// K3: out = h_cat(81920x512 f16, frag layout) @ W3p + out_b -> fp32 (B,10,512)
// 1280 blocks x 512 thr; block tile 64 rows x 512 cols; wave: 64x64.
// ---------------------------------------------------------------------------
__global__ __launch_bounds__(512) void out_gemm(
    const f16* __restrict__ hcat, const f16* __restrict__ W3p,
    const float* __restrict__ out_b, float* __restrict__ out) {
    const int mt0  = blockIdx.x << 2;
    const int wave = threadIdx.x >> 6;
    const int lane = threadIdx.x & 63;
    const int l16  = lane & 15;
    const int quad = lane >> 4;
    const int n0   = wave * 64;

    float bias_l[4];
#pragma unroll
    for (int nt = 0; nt < 4; ++nt) bias_l[nt] = out_b[n0 + nt * 16 + l16];

    f32x4 acc[4][4];
#pragma unroll
    for (int m = 0; m < 4; ++m)
#pragma unroll
        for (int nt = 0; nt < 4; ++nt)
#pragma unroll
            for (int q = 0; q < 4; ++q) acc[m][nt][q] = bias_l[nt];

#pragma unroll 2
    for (int kc = 0; kc < 16; ++kc) {
        f16x8 a[4], b[4];
#pragma unroll
        for (int m = 0; m < 4; ++m)
            a[m] = *(const f16x8*)(hcat + ((size_t)((mt0 + m) * 16 + kc) * 512 + lane * 8));
#pragma unroll
        for (int nt = 0; nt < 4; ++nt)
            b[nt] = *(const f16x8*)(W3p + ((kc * 32 + wave * 4 + nt) * 512 + lane * 8));
#pragma unroll
        for (int m = 0; m < 4; ++m)
#pragma unroll
            for (int nt = 0; nt < 4; ++nt)
                acc[m][nt] = __builtin_amdgcn_mfma_f32_16x16x32_f16(a[m], b[nt], acc[m][nt], 0, 0, 0);
    }

#pragma unroll
    for (int m = 0; m < 4; ++m) {
#pragma unroll
        for (int nt = 0; nt < 4; ++nt) {
#pragma unroll
            for (int q = 0; q < 4; ++q) {
                int R = mt0 * 16 + m * 16 + quad * 4 + q;
                int t = R >> 13;
                int b = R & 8191;
                out[(size_t)(b * 10 + t) * 512 + n0 + nt * 16 + l16] = acc[m][nt][q];
            }
        }
    }
}

// ---------------------------------------------------------------------------
extern "C" void kernel_launch(void* const* d_in, const int* in_sizes, int n_in,
                              void* d_out, int out_size, void* d_ws, size_t ws_size,
                              hipStream_t stream) {
    const int*   words   = (const int*)d_in[0];
    const int*   lengths = (const int*)d_in[1];
    const float* tab     = (const float*)d_in[2];
    const float* enc_w   = (const float*)d_in[3];
    const float* enc_b   = (const float*)d_in[4];
    const float* wih_f   = (const float*)d_in[5];
    const float* whh_f   = (const float*)d_in[6];
    const float* bih_f   = (const float*)d_in[7];
    const float* bhh_f   = (const float*)d_in[8];
    const float* wih_b   = (const float*)d_in[9];
    const float* whh_b   = (const float*)d_in[10];
    const float* bih_b   = (const float*)d_in[11];
    const float* bhh_b   = (const float*)d_in[12];
    const float* out_w   = (const float*)d_in[13];
    const float* out_b   = (const float*)d_in[14];
    float* out = (float*)d_out;

    char* ws = (char*)d_ws;
    f16*   Wp   = (f16*)(ws + 0);           //  2 MB
    f16*   W3p  = (f16*)(ws + 2097152);     //  0.5 MB
    float* bp   = (float*)(ws + 2621440);   //  8 KB
    float* P    = (float*)(ws + 2629632);   //  36 KB
    f16*   seqp = (f16*)(ws + 2666496);     //  40 MB
    f16*   hcat = (f16*)(ws + 44609536);    //  80 MB  (total ~122.6 MB)

    pack_w2<<<4096, 256, 0, stream>>>(wih_f, whh_f, wih_b, whh_b, Wp);
    pack_bias<<<8, 256, 0, stream>>>(bih_f, bhh_f, bih_b, bhh_b, bp);
    pack_w3<<<1024, 256, 0, stream>>>(out_w, W3p);
    enc_proj<<<36, 256, 0, stream>>>(tab, enc_w, enc_b, P);
    build_seq<<<10240, 256, 0, stream>>>(words, lengths, P, seqp);
    lstm_fused<<<256, 512, 0, stream>>>(seqp, Wp, bp, hcat);
    out_gemm<<<1280, 512, 0, stream>>>(hcat, W3p, out_b, out);
}